// Round 4
// baseline (456.602 us; speedup 1.0000x reference)
//
#include <hip/hip_runtime.h>

// AdvectionLayer: bilinear warp of image [B=8,C=4,H=1024,W=1024] by flow [B,2,H,W].
//
// R1: planar gather, TA/line-fill limited, 274 us.
// R2: fp32 interleaved ws, 4 float4 gathers -> 145 us. ~170 cyc/divergent-load/wave.
// R3: fp16 interleaved ws, 2 gathers -> ~73 us + 45 us interleave. Cost scales with
//     divergent-load COUNT (wave footprint ~50 lines regardless of pixel size).
// R4: fused single kernel. Per 32x32 tile, stage the 85x85 halo region (planar fp32
//     -> channel-interleaved fp16) into LDS with coalesced loads, then gather from
//     LDS (bank conflicts ~free for random addrs). Jitter bound |disp|<=26 px holds
//     for N(0,16) flow at 8M samples (~5.5 sigma max); out-of-region lanes take a
//     (never-in-practice) correct global fallback, so the halo is perf-only.

#define BB 8
#define CC 4
#define HH 1024
#define WW 1024
#define HW (HH * WW)

#define TILE 32
#define HALO 26
#define REG 85            // TILE + 2*HALO + 1 (for the +1 tap)
#define SLOT_MAX 83       // slot and slot+1 must be <= REG-1

typedef _Float16 h4 __attribute__((ext_vector_type(4)));  // one pixel, 8 B

__global__ __launch_bounds__(256) void advect_fused_kernel(
    const float* __restrict__ image,
    const float* __restrict__ flow,
    float* __restrict__ out)
{
    __shared__ h4 tile[REG * REG];   // 57800 B -> 2 blocks/CU

    const int b  = blockIdx.z;
    const int x0 = blockIdx.x * TILE;
    const int y0 = blockIdx.y * TILE;
    const int rx0 = x0 - HALO;
    const int ry0 = y0 - HALO;

    const float* imgb = image + (size_t)b * CC * HW;

    // ---- stage halo region: planar fp32 -> interleaved fp16 in LDS ----
    for (int i = threadIdx.x; i < REG * REG; i += 256) {
        int r = i / REG;
        int c = i - r * REG;
        int gy = min(max(ry0 + r, 0), HH - 1);   // border rows/cols duplicated
        int gx = min(max(rx0 + c, 0), WW - 1);
        const float* p = imgb + gy * WW + gx;
        h4 v;
        v.x = (_Float16)p[0];
        v.y = (_Float16)p[HW];
        v.z = (_Float16)p[2 * HW];
        v.w = (_Float16)p[3 * HW];
        tile[i] = v;
    }
    __syncthreads();

    const int tx = threadIdx.x & 31;
    const int ty = threadIdx.x >> 5;           // 0..7
    const int x  = x0 + tx;

    const float sxc = (float)WW / (float)(WW - 1);
    const float syc = (float)HH / (float)(HH - 1);

#pragma unroll
    for (int k = 0; k < 4; ++k) {
        int y = y0 + ty + k * 8;

        const float* fl = flow + (size_t)b * 2 * HW + (size_t)y * WW + x;
        float fx = fl[0];
        float fy = fl[HW];

        float ix = ((float)x + fx) * sxc - 0.5f;
        float iy = ((float)y + fy) * syc - 0.5f;
        ix = fminf(fmaxf(ix, 0.0f), (float)(WW - 1));
        iy = fminf(fmaxf(iy, 0.0f), (float)(HH - 1));

        int xl = min((int)ix, WW - 2);
        int yl = min((int)iy, HH - 2);
        float wx = ix - (float)xl;
        float wy = iy - (float)yl;

        float u0 = 1.0f - wx, v0 = 1.0f - wy;
        float w00 = v0 * u0, w01 = v0 * wx, w10 = wy * u0, w11 = wy * wx;

        int s = xl - rx0;
        int t = yl - ry0;

        float r0, r1, r2, r3;
        if ((unsigned)s <= SLOT_MAX && (unsigned)t <= SLOT_MAX) {
            const h4 a00 = tile[t * REG + s];
            const h4 a01 = tile[t * REG + s + 1];
            const h4 a10 = tile[(t + 1) * REG + s];
            const h4 a11 = tile[(t + 1) * REG + s + 1];
            r0 = w00 * (float)a00.x + w01 * (float)a01.x + w10 * (float)a10.x + w11 * (float)a11.x;
            r1 = w00 * (float)a00.y + w01 * (float)a01.y + w10 * (float)a10.y + w11 * (float)a11.y;
            r2 = w00 * (float)a00.z + w01 * (float)a01.z + w10 * (float)a10.z + w11 * (float)a11.z;
            r3 = w00 * (float)a00.w + w01 * (float)a01.w + w10 * (float)a10.w + w11 * (float)a11.w;
        } else {
            // correct-but-cold fallback: direct planar fp32 gather
            int o00 = yl * WW + xl;
            int o01 = o00 + 1;
            int o10 = o00 + WW;
            int o11 = o10 + 1;
            r0 = w00 * imgb[o00] + w01 * imgb[o01] + w10 * imgb[o10] + w11 * imgb[o11];
            r1 = w00 * imgb[HW + o00] + w01 * imgb[HW + o01] + w10 * imgb[HW + o10] + w11 * imgb[HW + o11];
            r2 = w00 * imgb[2 * HW + o00] + w01 * imgb[2 * HW + o01] + w10 * imgb[2 * HW + o10] + w11 * imgb[2 * HW + o11];
            r3 = w00 * imgb[3 * HW + o00] + w01 * imgb[3 * HW + o01] + w10 * imgb[3 * HW + o10] + w11 * imgb[3 * HW + o11];
        }

        float* ob = out + (size_t)b * CC * HW + (size_t)y * WW + x;
        ob[0] = r0;
        ob[HW] = r1;
        ob[2 * HW] = r2;
        ob[3 * HW] = r3;
    }
}

extern "C" void kernel_launch(void* const* d_in, const int* in_sizes, int n_in,
                              void* d_out, int out_size, void* d_ws, size_t ws_size,
                              hipStream_t stream) {
    const float* image = (const float*)d_in[0];
    const float* flow  = (const float*)d_in[1];
    float* out = (float*)d_out;

    dim3 grid(WW / TILE, HH / TILE, BB);   // 32 x 32 x 8 blocks, 256 thr each
    advect_fused_kernel<<<grid, 256, 0, stream>>>(image, flow, out);
}